// Round 5
// baseline (2856.389 us; speedup 1.0000x reference)
//
#include <hip/hip_runtime.h>
#include <hip/hip_fp16.h>
#include <hip/hip_cooperative_groups.h>
#include <math.h>

namespace cg = cooperative_groups;

#define NN    6000
#define NPAD  6144
#define NIB   1200
#define NMAXI 80
#define NAVGI 30
#define NBLK  250
#define NTHR  768   // 12 waves/block, 2 rows per wave -> 24 rows/block, 250 blocks

// float(np.sqrt(np.pi))
#define SQRT_PI_F 1.7724538509055160273f

typedef _Float16 half2_t __attribute__((ext_vector_type(2)));

__device__ __forceinline__ float erfcx_ref(float y) {
  // mirrors reference: clip, small/large branches, negative reflection
  y = fminf(fmaxf(y, -9.0f), 25.0f);
  float a   = fabsf(y);
  float a_s = fminf(a, 5.0f);
  float fsm = expf(a_s * a_s) * erfcf(a_s);
  float a_l = fmaxf(a, 5.0f);
  float flg = (1.0f / (SQRT_PI_F * a_l)) * (1.0f - 0.5f / (a_l * a_l));
  float f   = (a <= 5.0f) ? fsm : flg;
  return (y >= 0.0f) ? f : 2.0f * expf(y * y) - f;
}

__device__ __forceinline__ float dot2acc(unsigned w, unsigned r, float acc) {
#if defined(__has_builtin) && __has_builtin(__builtin_amdgcn_fdot2)
  return __builtin_amdgcn_fdot2(__builtin_bit_cast(half2_t, w),
                                __builtin_bit_cast(half2_t, r), acc, false);
#else
  half2_t wh = __builtin_bit_cast(half2_t, w);
  half2_t rh = __builtin_bit_cast(half2_t, r);
  return acc + (float)wh.x * (float)rh.x + (float)wh.y * (float)rh.y;
#endif
}

__device__ __forceinline__ unsigned pksq(unsigned w) {
  half2_t wh = __builtin_bit_cast(half2_t, w);
  half2_t s  = wh * wh;                 // v_pk_mul_f16
  return __builtin_bit_cast(unsigned, s);
}

__global__ __launch_bounds__(256) void init_kernel(
    const float* __restrict__ contrast, const float* __restrict__ grat,
    const float* __restrict__ pref, float* __restrict__ g0,
    float* __restrict__ g1, float* __restrict__ meanv,
    float* __restrict__ ctab, float* __restrict__ qn, float* __restrict__ qw,
    unsigned* __restrict__ conv)
{
  int t = blockIdx.x * 256 + threadIdx.x;
  if (t < NPAD) { g0[t] = 0.0f; g1[t] = 0.0f; }   // r0 = 0, pads = 0
  if (t < NN) {
    double th = (3.141592653589793 - 0.01) * (double)t / 5999.0;
    ctab[t] = cosf(2.0f * (float)th) - 1.0f;
    float d  = grat[0] - pref[t];
    float cg = (cosf(d * 3.14159265358979323846f / 90.0f) - 1.0f) / 1.0966227112321508f;
    meanv[t] = contrast[0] * 20.0f * expf(cg);
  }
  if (t < NMAXI) conv[t] = 0u;
  // 64-pt Gauss-Legendre nodes/weights via Newton on Legendre recurrence (fp64)
  if (blockIdx.x == 0 && threadIdx.x < 64) {
    int m = threadIdx.x;
    double x = cos(3.141592653589793 * (m + 0.75) / 64.5);
    double p0, p1, dp = 1.0;
    for (int it = 0; it < 60; ++it) {
      p0 = 1.0; p1 = x;
      for (int k = 2; k <= 64; ++k) {
        double p2 = ((2.0 * k - 1.0) * x * p1 - (k - 1.0) * p0) / (double)k;
        p0 = p1; p1 = p2;
      }
      dp = 64.0 * (x * p1 - p0) / (x * x - 1.0);
      double step = p1 / dp;
      x -= step;
      if (fabs(step) < 1e-15) break;
    }
    p0 = 1.0; p1 = x;
    for (int k = 2; k <= 64; ++k) {
      double p2 = ((2.0 * k - 1.0) * x * p1 - (k - 1.0) * p0) / (double)k;
      p0 = p1; p1 = p2;
    }
    dp = 64.0 * (x * p1 - p0) / (x * x - 1.0);
    double wgt = 2.0 / ((1.0 - x * x) * dp * dp);
    qn[63 - m] = (float)x;
    qw[63 - m] = (float)wgt;
  }
}

// Generate one row of W into a NAMED register array (no pointer aliasing --
// pointer-based selection defeated SROA in round 4 and spilled W to scratch).
#define GENROW(WREG, ROW)                                                     \
  do {                                                                        \
    const int   ri_  = ((ROW) < NIB) ? 1 : 0;                                 \
    const float eA_ = hyper[0 + ri_], eB_ = hyper[2 + ri_];                   \
    const float pA_ = hyper[4 + ri_], pB_ = hyper[6 + ri_];                   \
    const float cdeg_ = 0.017453292519943295f;                                \
    const float wdA_ = cdeg_ * hyper[8 + ri_], wdB_ = cdeg_ * hyper[10 + ri_];\
    const float dA_ = 4.0f * (wdA_ * wdA_), dB_ = 4.0f * (wdB_ * wdB_);       \
    const float* urow_ = randu + (size_t)(ROW) * NN;                          \
    _Pragma("unroll")                                                         \
    for (int k_ = 0; k_ < 24; ++k_) {                                         \
      const int j0_ = k_ * 256 + (lane << 2);                                 \
      float w_[4] = {0.0f, 0.0f, 0.0f, 0.0f};                                 \
      if (j0_ + 3 < NN) {                                                     \
        const float4 uv_ = *reinterpret_cast<const float4*>(urow_ + j0_);     \
        const float us_[4] = {uv_.x, uv_.y, uv_.z, uv_.w};                    \
        _Pragma("unroll")                                                     \
        for (int q_ = 0; q_ < 4; ++q_) {                                      \
          const int j_ = j0_ + q_;                                            \
          int idx_ = j_ - (ROW); idx_ += (idx_ < 0) ? NN : 0;                 \
          const float ct_   = ctabs[idx_];                                    \
          const float eff_  = (j_   < NIB) ? eB_ : eA_;                       \
          const float prob_ = (j_   < NIB) ? pB_ : pA_;                       \
          const float den_  = (idx_ < NIB) ? dB_ : dA_;                       \
          const float Z_  = expf(ct_ / den_);                                 \
          const float tt_ = 32.0f * (prob_ * Z_ - us_[q_]);                   \
          w_[q_] = eff_ / (1.0f + expf(-tt_));                                \
        }                                                                     \
      }                                                                       \
      half2_t h01_; h01_.x = (_Float16)w_[0]; h01_.y = (_Float16)w_[1];       \
      half2_t h23_; h23_.x = (_Float16)w_[2]; h23_.y = (_Float16)w_[3];       \
      WREG[k_].x = __builtin_bit_cast(unsigned, h01_);                        \
      WREG[k_].y = __builtin_bit_cast(unsigned, h23_);                        \
    }                                                                         \
  } while (0)

// Persistent cooperative kernel. 250 blocks x 768 threads = 1 block/CU,
// 3 waves/EU -> VGPR cap 170. Each wave owns TWO rows; W (fp16) lives in
// 96 VGPRs per thread. r staged in LDS as fp16; dot via v_dot2_f32_f16.
__global__ __launch_bounds__(NTHR, 3) void solve_kernel(
    const float* __restrict__ hyper, const float* __restrict__ randu,
    const float* __restrict__ ctab, const float* __restrict__ meanv,
    const float* __restrict__ qn, const float* __restrict__ qw,
    float* __restrict__ g0, float* __restrict__ g1,
    float* __restrict__ blkmax, float* __restrict__ out)
{
  cg::grid_group grid = cg::this_grid();

  const int tid  = threadIdx.x;
  const int lane = tid & 63;
  const int wv   = tid >> 6;
  const int rowA = blockIdx.x * 24 + wv * 2;
  const int rowB = rowA + 1;

  __shared__ float ctabs[NN];
  __shared__ uint2 rh2[NPAD / 4];     // fp16 r: rh2[i] = r[4i..4i+3]
  __shared__ float wmax[12];
  __shared__ float sflag[NAVGI];

  // stage ctab into LDS (one-time)
  {
    const float4* c4 = reinterpret_cast<const float4*>(ctab);
    float4* l4 = reinterpret_cast<float4*>(ctabs);
    for (int i = tid; i < NN / 4; i += NTHR) l4[i] = c4[i];
  }
  __syncthreads();

  const float qnl = qn[lane];
  const float qwl = qw[lane];
  const float meanA = meanv[rowA];
  const float meanB = meanv[rowB];

  // ---- generate both rows' W into registers (fp16, packed 2/uint) ----
  uint2 WA[24], WB[24];
  GENROW(WA, rowA);
  GENROW(WB, rowB);

  // ---- fixed-point iteration ----
  for (int t = 0; t < NMAXI; ++t) {
    const float* rcur = (t & 1) ? g1 : g0;
    float*       rnxt = (t & 1) ? g0 : g1;

    // stage r (fp32 global -> fp16 LDS), 8-byte lane stride (conflict-free)
    {
      const float4* rc4 = reinterpret_cast<const float4*>(rcur);
      const float4 s0 = rc4[tid];
      const float4 s1 = rc4[tid + NTHR];
      half2_t a, b, c2, d2;
      a.x  = (_Float16)s0.x; a.y  = (_Float16)s0.y;
      b.x  = (_Float16)s0.z; b.y  = (_Float16)s0.w;
      c2.x = (_Float16)s1.x; c2.y = (_Float16)s1.y;
      d2.x = (_Float16)s1.z; d2.y = (_Float16)s1.w;
      uint2 p0, p1;
      p0.x = __builtin_bit_cast(unsigned, a);
      p0.y = __builtin_bit_cast(unsigned, b);
      p1.x = __builtin_bit_cast(unsigned, c2);
      p1.y = __builtin_bit_cast(unsigned, d2);
      rh2[tid]        = p0;
      rh2[tid + NTHR] = p1;
    }
    __syncthreads();

    // fused W.r and (W*W).r for both rows, via v_dot2_f32_f16
    float muA = 0.0f, varA = 0.0f, muB = 0.0f, varB = 0.0f;
#pragma unroll
    for (int k = 0; k < 24; ++k) {
      const uint2 rr = rh2[k * 64 + lane];
      muA  = dot2acc(WA[k].x, rr.x, muA);
      muA  = dot2acc(WA[k].y, rr.y, muA);
      varA = dot2acc(pksq(WA[k].x), rr.x, varA);
      varA = dot2acc(pksq(WA[k].y), rr.y, varA);
      muB  = dot2acc(WB[k].x, rr.x, muB);
      muB  = dot2acc(WB[k].y, rr.y, muB);
      varB = dot2acc(pksq(WB[k].x), rr.x, varB);
      varB = dot2acc(pksq(WB[k].y), rr.y, varB);
    }
#pragma unroll
    for (int off = 32; off > 0; off >>= 1) {
      muA  += __shfl_xor(muA, off);
      varA += __shfl_xor(varA, off);
      muB  += __shfl_xor(muB, off);
      varB += __shfl_xor(varB, off);
    }

    float ratioM = 0.0f;
#pragma unroll
    for (int rr = 0; rr < 2; ++rr) {
      const int   row  = rr ? rowB : rowA;
      float mu  = (rr ? muB : muA)  + (rr ? meanB : meanA);
      float var = (rr ? varB : varA) + 25.0f;
      const float sig = sqrtf(var);
      const float uu = (20.0f - mu) / sig;
      const float ll = (10.0f - mu) / sig;
      const float cc = 0.5f * (uu + ll);
      const float hh = 0.5f * (uu - ll);
      const float x = cc + hh * qnl;
      float term    = qwl * erfcx_ref(-x);
#pragma unroll
      for (int off = 32; off > 0; off >>= 1) term += __shfl_xor(term, off);
      const float integ = hh * term;
      const float phiv  = 1.0f / (1.0f + SQRT_PI_F * fmaxf(integ, 0.0f));

      const float rold = rcur[row];           // exact fp32 state
      const float dx   = (phiv - rold) * 0.1f;
      const float rnew = rold + dx;
      ratioM = fmaxf(ratioM, fabsf(dx) / fmaxf(1.0f, fabsf(rnew)));
      if (lane == 0) {
        if (t == NMAXI - 1) out[row] = rnew;
        else                rnxt[row] = rnew;
      }
    }
    if (lane == 0) wmax[wv] = ratioM;
    __syncthreads();
    if (tid == 0) {
      float m = wmax[0];
#pragma unroll
      for (int q = 1; q < 12; ++q) m = fmaxf(m, wmax[q]);
      blkmax[(size_t)t * NBLK + blockIdx.x] = m;
    }
    grid.sync();
  }

  // ---- convergence epilogue: block 0 reduces blkmax over [50,80) ----
  if (blockIdx.x == 0) {
#pragma unroll
    for (int s = 0; s < 3; ++s) {
      const int t = 50 + wv + 12 * s;
      if (t < NMAXI) {
        float m = 0.0f;   // ratios are >= 0
        for (int p = lane; p < NBLK; p += 64)
          m = fmaxf(m, blkmax[(size_t)t * NBLK + p]);
#pragma unroll
        for (int off = 32; off > 0; off >>= 1)
          m = fmaxf(m, __shfl_xor(m, off));
        if (lane == 0) sflag[t - 50] = (m < 1e-5f) ? 1.0f : 0.0f;
      }
    }
    __syncthreads();
    if (tid == 0) {
      float s = 0.0f;
#pragma unroll
      for (int q = 0; q < NAVGI; ++q) s += sflag[q];
      out[NN] = s / 30.0f;
    }
  }
}

// ---------------- fallback path (round-2 structure, fp32 W in ws) ----------
__global__ __launch_bounds__(256) void genw_kernel(
    const float* __restrict__ hyper, const float* __restrict__ randu,
    const float* __restrict__ ctab, float* __restrict__ Wf)
{
  const int i  = blockIdx.x;
  const int ri = (i < NIB) ? 1 : 0;
  const float eA = hyper[0 + ri], eB = hyper[2 + ri];
  const float pA = hyper[4 + ri], pB = hyper[6 + ri];
  const float c  = 0.017453292519943295f;
  const float wA = c * hyper[8 + ri], wB = c * hyper[10 + ri];
  const float dA = 4.0f * (wA * wA), dB = 4.0f * (wB * wB);
  const float* urow = randu + (size_t)i * NN;
  for (int j4 = threadIdx.x * 4; j4 < NN; j4 += 1024) {
    float4 uv = *reinterpret_cast<const float4*>(urow + j4);
    float us[4] = {uv.x, uv.y, uv.z, uv.w};
    float res[4];
#pragma unroll
    for (int q = 0; q < 4; ++q) {
      int j   = j4 + q;
      int idx = j - i; idx += (idx < 0) ? NN : 0;
      float ct   = ctab[idx];
      float eff  = (j   < NIB) ? eB : eA;
      float prob = (j   < NIB) ? pB : pA;
      float den  = (idx < NIB) ? dB : dA;
      float Z  = expf(ct / den);
      float tt = 32.0f * (prob * Z - us[q]);
      res[q] = eff / (1.0f + expf(-tt));
    }
    *reinterpret_cast<float4*>(Wf + (size_t)i * NN + j4) =
        make_float4(res[0], res[1], res[2], res[3]);
  }
}

__global__ __launch_bounds__(256) void iter_kernel(
    const float* __restrict__ Wf, const float* __restrict__ rin,
    float* __restrict__ rout, const float* __restrict__ meanv,
    const float* __restrict__ qn, const float* __restrict__ qw,
    unsigned* __restrict__ convslot)
{
  const int row  = blockIdx.x;
  const int tid  = threadIdx.x;
  const int lane = tid & 63;
  const int wvid = tid >> 6;
  __shared__ float smu[4], svar[4];
  float mu = 0.0f, var = 0.0f;
  const float* wrow = Wf + (size_t)row * NN;
  float4 w[6], r4[6]; bool have[6];
#pragma unroll
  for (int k = 0; k < 6; ++k) {
    const int j = (tid << 2) + (k << 10);
    have[k] = (j < NN);
    if (have[k]) {
      w[k]  = *reinterpret_cast<const float4*>(wrow + j);
      r4[k] = *reinterpret_cast<const float4*>(rin + j);
    }
  }
#pragma unroll
  for (int k = 0; k < 6; ++k) if (have[k]) {
    mu  += w[k].x * r4[k].x + w[k].y * r4[k].y + w[k].z * r4[k].z + w[k].w * r4[k].w;
    var += w[k].x * w[k].x * r4[k].x + w[k].y * w[k].y * r4[k].y
         + w[k].z * w[k].z * r4[k].z + w[k].w * w[k].w * r4[k].w;
  }
#pragma unroll
  for (int off = 32; off > 0; off >>= 1) {
    mu  += __shfl_xor(mu, off);
    var += __shfl_xor(var, off);
  }
  if (lane == 0) { smu[wvid] = mu; svar[wvid] = var; }
  __syncthreads();
  if (tid < 64) {
    mu  = smu[0] + smu[1] + smu[2] + smu[3];
    var = svar[0] + svar[1] + svar[2] + svar[3];
    mu += meanv[row]; var += 25.0f;
    const float sig = sqrtf(var);
    const float uu = (20.0f - mu) / sig;
    const float ll = (10.0f - mu) / sig;
    const float cc = 0.5f * (uu + ll);
    const float hh = 0.5f * (uu - ll);
    const float x = cc + hh * qn[lane];
    float term    = qw[lane] * erfcx_ref(-x);
#pragma unroll
    for (int off = 32; off > 0; off >>= 1) term += __shfl_xor(term, off);
    const float integ = hh * term;
    const float phiv  = 1.0f / (1.0f + SQRT_PI_F * fmaxf(integ, 0.0f));
    const float rold = rin[row];
    const float dx   = (phiv - rold) * 0.1f;
    const float rnew = rold + dx;
    if (lane == 0) {
      rout[row] = rnew;
      const float ratio = fabsf(dx) / fmaxf(1.0f, fabsf(rnew));
      atomicMax(convslot, __float_as_uint(ratio));
    }
  }
}

__global__ __launch_bounds__(256) void final_kernel(
    const float* __restrict__ rfin, const unsigned* __restrict__ conv,
    float* __restrict__ out)
{
  int t = blockIdx.x * 256 + threadIdx.x;
  if (t < NN) out[t] = rfin[t];
  if (t == 6000) {
    float s = 0.0f;
    for (int k = NMAXI - NAVGI; k < NMAXI; ++k)
      s += (__uint_as_float(conv[k]) < 1e-5f) ? 1.0f : 0.0f;
    out[NN] = s / 30.0f;
  }
}

extern "C" void kernel_launch(void* const* d_in, const int* in_sizes, int n_in,
                              void* d_out, int out_size, void* d_ws, size_t ws_size,
                              hipStream_t stream) {
  const float* hyper    = (const float*)d_in[0];
  const float* contrast = (const float*)d_in[1];
  const float* grat     = (const float*)d_in[2];
  const float* pref     = (const float*)d_in[3];
  const float* randu    = (const float*)d_in[4];
  float* out = (float*)d_out;

  char* ws = (char*)d_ws;
  float*    g0     = (float*)(ws + 0);       // 6144 f (r buf A + pad)
  float*    g1     = (float*)(ws + 24576);   // 6144 f (r buf B + pad)
  float*    mn     = (float*)(ws + 49152);   // 6000 f
  float*    ctab   = (float*)(ws + 73152);   // 6000 f
  float*    qn     = (float*)(ws + 97152);   // 64 f
  float*    qw     = (float*)(ws + 97408);   // 64 f
  unsigned* conv   = (unsigned*)(ws + 97664);// 80 u32 (fallback)
  float*    blkmax = (float*)(ws + 98304);   // 80*250 f
  float*    Wf     = (float*)(ws + 262144);  // fallback fp32 W

  init_kernel<<<24, 256, 0, stream>>>(contrast, grat, pref, g0, g1, mn, ctab, qn, qw, conv);

  // cooperative persistent kernel: W in registers (fp16), 80 internal iters
  {
    const float* a_hyper = hyper;  const float* a_randu = randu;
    const float* a_ctab  = ctab;   const float* a_mn    = mn;
    const float* a_qn    = qn;     const float* a_qw    = qw;
    float* a_g0 = g0; float* a_g1 = g1; float* a_bm = blkmax; float* a_out = out;
    void* args[10] = {&a_hyper, &a_randu, &a_ctab, &a_mn, &a_qn, &a_qw,
                      &a_g0, &a_g1, &a_bm, &a_out};
    hipError_t err = hipLaunchCooperativeKernel(
        (const void*)solve_kernel, dim3(NBLK), dim3(NTHR), args, 0, stream);
    if (err == hipSuccess) return;
  }

  // fallback: round-2 structure
  genw_kernel<<<NN, 256, 0, stream>>>(hyper, randu, ctab, Wf);
  float* rb[2] = {g0, g1};
  for (int t = 0; t < NMAXI; ++t) {
    const float* rin = rb[t & 1];
    float*       rou = rb[(t + 1) & 1];
    iter_kernel<<<NN, 256, 0, stream>>>(Wf, rin, rou, mn, qn, qw, conv + t);
  }
  final_kernel<<<24, 256, 0, stream>>>(rb[0], conv, out);
}

// Round 6
// 1651.916 us; speedup vs baseline: 1.7291x; 1.7291x over previous
//
#include <hip/hip_runtime.h>
#include <hip/hip_fp16.h>
#include <math.h>

#define NN    6000
#define NPAD  6144
#define NIB   1200
#define NMAXI 80
#define NAVGI 30
#define NBLK  250
#define NTHR  768   // 12 waves/block, 2 rows per wave -> 24 rows/block, 250 blocks

// float(np.sqrt(np.pi))
#define SQRT_PI_F 1.7724538509055160273f

typedef _Float16 half2_t __attribute__((ext_vector_type(2)));
typedef unsigned uvec8  __attribute__((ext_vector_type(8)));

__device__ __forceinline__ float erfcx_ref(float y) {
  // mirrors reference: clip, small/large branches, negative reflection
  y = fminf(fmaxf(y, -9.0f), 25.0f);
  float a   = fabsf(y);
  float a_s = fminf(a, 5.0f);
  float fsm = expf(a_s * a_s) * erfcf(a_s);
  float a_l = fmaxf(a, 5.0f);
  float flg = (1.0f / (SQRT_PI_F * a_l)) * (1.0f - 0.5f / (a_l * a_l));
  float f   = (a <= 5.0f) ? fsm : flg;
  return (y >= 0.0f) ? f : 2.0f * expf(y * y) - f;
}

__device__ __forceinline__ float dot2acc(unsigned w, unsigned r, float acc) {
#if defined(__has_builtin) && __has_builtin(__builtin_amdgcn_fdot2)
  return __builtin_amdgcn_fdot2(__builtin_bit_cast(half2_t, w),
                                __builtin_bit_cast(half2_t, r), acc, false);
#else
  half2_t wh = __builtin_bit_cast(half2_t, w);
  half2_t rh = __builtin_bit_cast(half2_t, r);
  return acc + (float)wh.x * (float)rh.x + (float)wh.y * (float)rh.y;
#endif
}

__device__ __forceinline__ unsigned pksq(unsigned w) {
  half2_t wh = __builtin_bit_cast(half2_t, w);
  half2_t s  = wh * wh;                 // v_pk_mul_f16
  return __builtin_bit_cast(unsigned, s);
}

// Inline sense-reversing global barrier. No function call => values stay in
// VGPRs across it. Agent-scope fences give cross-XCD visibility
// (release -> buffer_wbl2 sc1, acquire -> buffer_inv sc1 on gfx95x).
__device__ __forceinline__ void gbar(unsigned* cnt, unsigned* gen, int tid) {
  __syncthreads();   // all block stores issued (vmcnt drained)
  if (tid == 0) {
    __builtin_amdgcn_fence(__ATOMIC_RELEASE, "agent");
    const unsigned g = __hip_atomic_load(gen, __ATOMIC_RELAXED,
                                         __HIP_MEMORY_SCOPE_AGENT);
    const unsigned old = __hip_atomic_fetch_add(cnt, 1u, __ATOMIC_RELAXED,
                                                __HIP_MEMORY_SCOPE_AGENT);
    if (old == NBLK - 1) {
      __hip_atomic_store(cnt, 0u, __ATOMIC_RELAXED, __HIP_MEMORY_SCOPE_AGENT);
      __hip_atomic_store(gen, g + 1u, __ATOMIC_RELEASE,
                         __HIP_MEMORY_SCOPE_AGENT);
    } else {
      while (__hip_atomic_load(gen, __ATOMIC_RELAXED,
                               __HIP_MEMORY_SCOPE_AGENT) == g)
        __builtin_amdgcn_s_sleep(2);
    }
    __builtin_amdgcn_fence(__ATOMIC_ACQUIRE, "agent");
  }
  __syncthreads();
}

__global__ __launch_bounds__(256) void init_kernel(
    const float* __restrict__ contrast, const float* __restrict__ grat,
    const float* __restrict__ pref, float* __restrict__ g0,
    float* __restrict__ g1, float* __restrict__ meanv,
    float* __restrict__ ctab, float* __restrict__ qn, float* __restrict__ qw,
    unsigned* __restrict__ conv, unsigned* __restrict__ bar)
{
  int t = blockIdx.x * 256 + threadIdx.x;
  if (t < NPAD) { g0[t] = 0.0f; g1[t] = 0.0f; }   // r0 = 0, pads = 0
  if (t < NN) {
    double th = (3.141592653589793 - 0.01) * (double)t / 5999.0;
    ctab[t] = cosf(2.0f * (float)th) - 1.0f;
    float d  = grat[0] - pref[t];
    float cg = (cosf(d * 3.14159265358979323846f / 90.0f) - 1.0f) / 1.0966227112321508f;
    meanv[t] = contrast[0] * 20.0f * expf(cg);
  }
  if (t < NMAXI) conv[t] = 0u;
  if (t < 2)     bar[t]  = 0u;     // barrier cnt / gen (re-zeroed every call)
  // 64-pt Gauss-Legendre nodes/weights via Newton on Legendre recurrence (fp64)
  if (blockIdx.x == 0 && threadIdx.x < 64) {
    int m = threadIdx.x;
    double x = cos(3.141592653589793 * (m + 0.75) / 64.5);
    double p0, p1, dp = 1.0;
    for (int it = 0; it < 60; ++it) {
      p0 = 1.0; p1 = x;
      for (int k = 2; k <= 64; ++k) {
        double p2 = ((2.0 * k - 1.0) * x * p1 - (k - 1.0) * p0) / (double)k;
        p0 = p1; p1 = p2;
      }
      dp = 64.0 * (x * p1 - p0) / (x * x - 1.0);
      double step = p1 / dp;
      x -= step;
      if (fabs(step) < 1e-15) break;
    }
    p0 = 1.0; p1 = x;
    for (int k = 2; k <= 64; ++k) {
      double p2 = ((2.0 * k - 1.0) * x * p1 - (k - 1.0) * p0) / (double)k;
      p0 = p1; p1 = p2;
    }
    dp = 64.0 * (x * p1 - p0) / (x * x - 1.0);
    double wgt = 2.0 / ((1.0 - x * x) * dp * dp);
    qn[63 - m] = (float)x;
    qw[63 - m] = (float)wgt;
  }
}

// Generate 4 chunks (one uvec8) of row ROW's W into named vector WV.
// All indices compile-time after unroll; WV is a named SSA vector value.
#define GENV(WV, ROW, V, EI, EE, PI, PE, DI, DE, UROW)                        \
  do {                                                                        \
    _Pragma("unroll")                                                         \
    for (int c_ = 0; c_ < 4; ++c_) {                                          \
      const int k_  = (V) * 4 + c_;                                           \
      const int j0_ = k_ * 256 + (lane << 2);                                 \
      float w_[4] = {0.0f, 0.0f, 0.0f, 0.0f};                                 \
      if (j0_ + 3 < NN) {                                                     \
        const float4 uv_ = *reinterpret_cast<const float4*>((UROW) + j0_);    \
        const float us_[4] = {uv_.x, uv_.y, uv_.z, uv_.w};                    \
        _Pragma("unroll")                                                     \
        for (int q_ = 0; q_ < 4; ++q_) {                                      \
          const int j_ = j0_ + q_;                                            \
          int idx_ = j_ - (ROW); idx_ += (idx_ < 0) ? NN : 0;                 \
          const float ct_   = ctabs[idx_];                                    \
          const float eff_  = (j_   < NIB) ? (EI) : (EE);                     \
          const float prob_ = (j_   < NIB) ? (PI) : (PE);                     \
          const float den_  = (idx_ < NIB) ? (DI) : (DE);                     \
          const float Z_  = expf(ct_ / den_);                                 \
          const float tt_ = 32.0f * (prob_ * Z_ - us_[q_]);                   \
          w_[q_] = eff_ / (1.0f + expf(-tt_));                                \
        }                                                                     \
      }                                                                       \
      half2_t h01_; h01_.x = (_Float16)w_[0]; h01_.y = (_Float16)w_[1];       \
      half2_t h23_; h23_.x = (_Float16)w_[2]; h23_.y = (_Float16)w_[3];       \
      WV[2 * c_]     = __builtin_bit_cast(unsigned, h01_);                    \
      WV[2 * c_ + 1] = __builtin_bit_cast(unsigned, h23_);                    \
    }                                                                         \
  } while (0)

// Accumulate 4 chunks for both rows from one LDS read per chunk.
#define ACC2(WAV, WBV, V)                                                     \
  do {                                                                        \
    _Pragma("unroll")                                                         \
    for (int c_ = 0; c_ < 4; ++c_) {                                          \
      const uint2 rr_ = rh2[((V) * 4 + c_) * 64 + lane];                      \
      muA  = dot2acc(WAV[2 * c_],       rr_.x, muA);                          \
      muA  = dot2acc(WAV[2 * c_ + 1],   rr_.y, muA);                          \
      varA = dot2acc(pksq(WAV[2 * c_]),     rr_.x, varA);                     \
      varA = dot2acc(pksq(WAV[2 * c_ + 1]), rr_.y, varA);                     \
      muB  = dot2acc(WBV[2 * c_],       rr_.x, muB);                          \
      muB  = dot2acc(WBV[2 * c_ + 1],   rr_.y, muB);                          \
      varB = dot2acc(pksq(WBV[2 * c_]),     rr_.x, varB);                     \
      varB = dot2acc(pksq(WBV[2 * c_ + 1]), rr_.y, varB);                     \
    }                                                                         \
  } while (0)

// Persistent kernel. 250 blocks x 768 threads = 1 block/CU, 3 waves/EU
// (VGPR cap 168). Each wave owns TWO rows; W (fp16) in 12 named uvec8
// vectors (96 VGPRs). Inline global barrier (no call => no spill).
__global__ __launch_bounds__(NTHR, 3) void solve_kernel(
    const float* __restrict__ hyper, const float* __restrict__ randu,
    const float* __restrict__ ctab, const float* __restrict__ meanv,
    const float* __restrict__ qn, const float* __restrict__ qw,
    float* __restrict__ g0, float* __restrict__ g1,
    float* __restrict__ blkmax, unsigned* __restrict__ bar,
    float* __restrict__ out)
{
  const int tid  = threadIdx.x;
  const int lane = tid & 63;
  const int wv   = tid >> 6;
  const int rowA = blockIdx.x * 24 + wv * 2;
  const int rowB = rowA + 1;

  __shared__ float ctabs[NN];
  __shared__ uint2 rh2[NPAD / 4];     // fp16 r: rh2[i] = r[4i..4i+3]
  __shared__ float wmax[12];
  __shared__ float sflag[NAVGI];

  // stage ctab into LDS (one-time)
  {
    const float4* c4 = reinterpret_cast<const float4*>(ctab);
    float4* l4 = reinterpret_cast<float4*>(ctabs);
    for (int i = tid; i < NN / 4; i += NTHR) l4[i] = c4[i];
  }
  __syncthreads();

  const float qnl = qn[lane];
  const float qwl = qw[lane];
  const float meanA = meanv[rowA];
  const float meanB = meanv[rowB];

  // ---- generate both rows' W into named register vectors ----
  uvec8 wa0, wa1, wa2, wa3, wa4, wa5, wb0, wb1, wb2, wb3, wb4, wb5;
  {
    const int   riA = (rowA < NIB) ? 1 : 0;
    const float eIa = hyper[2 + riA], eEa = hyper[0 + riA];
    const float pIa = hyper[6 + riA], pEa = hyper[4 + riA];
    const float cdg = 0.017453292519943295f;
    const float wIa = cdg * hyper[10 + riA], wEa = cdg * hyper[8 + riA];
    const float dIa = 4.0f * (wIa * wIa), dEa = 4.0f * (wEa * wEa);
    const float* urA = randu + (size_t)rowA * NN;
    GENV(wa0, rowA, 0, eIa, eEa, pIa, pEa, dIa, dEa, urA);
    GENV(wa1, rowA, 1, eIa, eEa, pIa, pEa, dIa, dEa, urA);
    GENV(wa2, rowA, 2, eIa, eEa, pIa, pEa, dIa, dEa, urA);
    GENV(wa3, rowA, 3, eIa, eEa, pIa, pEa, dIa, dEa, urA);
    GENV(wa4, rowA, 4, eIa, eEa, pIa, pEa, dIa, dEa, urA);
    GENV(wa5, rowA, 5, eIa, eEa, pIa, pEa, dIa, dEa, urA);
    const int   riB = (rowB < NIB) ? 1 : 0;
    const float eIb = hyper[2 + riB], eEb = hyper[0 + riB];
    const float pIb = hyper[6 + riB], pEb = hyper[4 + riB];
    const float wIb = cdg * hyper[10 + riB], wEb = cdg * hyper[8 + riB];
    const float dIb = 4.0f * (wIb * wIb), dEb = 4.0f * (wEb * wEb);
    const float* urB = randu + (size_t)rowB * NN;
    GENV(wb0, rowB, 0, eIb, eEb, pIb, pEb, dIb, dEb, urB);
    GENV(wb1, rowB, 1, eIb, eEb, pIb, pEb, dIb, dEb, urB);
    GENV(wb2, rowB, 2, eIb, eEb, pIb, pEb, dIb, dEb, urB);
    GENV(wb3, rowB, 3, eIb, eEb, pIb, pEb, dIb, dEb, urB);
    GENV(wb4, rowB, 4, eIb, eEb, pIb, pEb, dIb, dEb, urB);
    GENV(wb5, rowB, 5, eIb, eEb, pIb, pEb, dIb, dEb, urB);
  }

  // ---- fixed-point iteration ----
#pragma unroll 1
  for (int t = 0; t < NMAXI; ++t) {
    const float* rcur = (t & 1) ? g1 : g0;
    float*       rnxt = (t & 1) ? g0 : g1;

    // stage r (fp32 global -> fp16 LDS), 8-byte lane stride
    {
      const float4* rc4 = reinterpret_cast<const float4*>(rcur);
      const float4 s0 = rc4[tid];
      const float4 s1 = rc4[tid + NTHR];
      half2_t a, b, c2, d2;
      a.x  = (_Float16)s0.x; a.y  = (_Float16)s0.y;
      b.x  = (_Float16)s0.z; b.y  = (_Float16)s0.w;
      c2.x = (_Float16)s1.x; c2.y = (_Float16)s1.y;
      d2.x = (_Float16)s1.z; d2.y = (_Float16)s1.w;
      uint2 p0, p1;
      p0.x = __builtin_bit_cast(unsigned, a);
      p0.y = __builtin_bit_cast(unsigned, b);
      p1.x = __builtin_bit_cast(unsigned, c2);
      p1.y = __builtin_bit_cast(unsigned, d2);
      rh2[tid]        = p0;
      rh2[tid + NTHR] = p1;
    }
    __syncthreads();

    // fused W.r and (W*W).r for both rows, via v_dot2_f32_f16
    float muA = 0.0f, varA = 0.0f, muB = 0.0f, varB = 0.0f;
    ACC2(wa0, wb0, 0);
    ACC2(wa1, wb1, 1);
    ACC2(wa2, wb2, 2);
    ACC2(wa3, wb3, 3);
    ACC2(wa4, wb4, 4);
    ACC2(wa5, wb5, 5);
#pragma unroll
    for (int off = 32; off > 0; off >>= 1) {
      muA  += __shfl_xor(muA, off);
      varA += __shfl_xor(varA, off);
      muB  += __shfl_xor(muB, off);
      varB += __shfl_xor(varB, off);
    }

    float ratioM = 0.0f;
#pragma unroll
    for (int rr = 0; rr < 2; ++rr) {
      const int   row  = rr ? rowB : rowA;
      float mu  = (rr ? muB : muA)  + (rr ? meanB : meanA);
      float var = (rr ? varB : varA) + 25.0f;
      const float sig = sqrtf(var);
      const float uu = (20.0f - mu) / sig;
      const float ll = (10.0f - mu) / sig;
      const float cc = 0.5f * (uu + ll);
      const float hh = 0.5f * (uu - ll);
      const float x = cc + hh * qnl;
      float term    = qwl * erfcx_ref(-x);
#pragma unroll
      for (int off = 32; off > 0; off >>= 1) term += __shfl_xor(term, off);
      const float integ = hh * term;
      const float phiv  = 1.0f / (1.0f + SQRT_PI_F * fmaxf(integ, 0.0f));

      const float rold = rcur[row];           // exact fp32 state
      const float dx   = (phiv - rold) * 0.1f;
      const float rnew = rold + dx;
      ratioM = fmaxf(ratioM, fabsf(dx) / fmaxf(1.0f, fabsf(rnew)));
      if (lane == 0) {
        if (t == NMAXI - 1) out[row] = rnew;
        else                rnxt[row] = rnew;
      }
    }
    if (lane == 0) wmax[wv] = ratioM;
    __syncthreads();
    if (tid == 0) {
      float m = wmax[0];
#pragma unroll
      for (int q = 1; q < 12; ++q) m = fmaxf(m, wmax[q]);
      blkmax[(size_t)t * NBLK + blockIdx.x] = m;
    }
    gbar(bar, bar + 1, tid);
  }

  // ---- convergence epilogue: block 0 reduces blkmax over [50,80) ----
  if (blockIdx.x == 0) {
#pragma unroll
    for (int s = 0; s < 3; ++s) {
      const int t = 50 + wv + 12 * s;
      if (t < NMAXI) {
        float m = 0.0f;   // ratios are >= 0
        for (int p = lane; p < NBLK; p += 64)
          m = fmaxf(m, blkmax[(size_t)t * NBLK + p]);
#pragma unroll
        for (int off = 32; off > 0; off >>= 1)
          m = fmaxf(m, __shfl_xor(m, off));
        if (lane == 0) sflag[t - 50] = (m < 1e-5f) ? 1.0f : 0.0f;
      }
    }
    __syncthreads();
    if (tid == 0) {
      float s = 0.0f;
#pragma unroll
      for (int q = 0; q < NAVGI; ++q) s += sflag[q];
      out[NN] = s / 30.0f;
    }
  }
}

// ---------------- fallback path (round-2 structure, fp32 W in ws) ----------
__global__ __launch_bounds__(256) void genw_kernel(
    const float* __restrict__ hyper, const float* __restrict__ randu,
    const float* __restrict__ ctab, float* __restrict__ Wf)
{
  const int i  = blockIdx.x;
  const int ri = (i < NIB) ? 1 : 0;
  const float eA = hyper[0 + ri], eB = hyper[2 + ri];
  const float pA = hyper[4 + ri], pB = hyper[6 + ri];
  const float c  = 0.017453292519943295f;
  const float wA = c * hyper[8 + ri], wB = c * hyper[10 + ri];
  const float dA = 4.0f * (wA * wA), dB = 4.0f * (wB * wB);
  const float* urow = randu + (size_t)i * NN;
  for (int j4 = threadIdx.x * 4; j4 < NN; j4 += 1024) {
    float4 uv = *reinterpret_cast<const float4*>(urow + j4);
    float us[4] = {uv.x, uv.y, uv.z, uv.w};
    float res[4];
#pragma unroll
    for (int q = 0; q < 4; ++q) {
      int j   = j4 + q;
      int idx = j - i; idx += (idx < 0) ? NN : 0;
      float ct   = ctab[idx];
      float eff  = (j   < NIB) ? eB : eA;
      float prob = (j   < NIB) ? pB : pA;
      float den  = (idx < NIB) ? dB : dA;
      float Z  = expf(ct / den);
      float tt = 32.0f * (prob * Z - us[q]);
      res[q] = eff / (1.0f + expf(-tt));
    }
    *reinterpret_cast<float4*>(Wf + (size_t)i * NN + j4) =
        make_float4(res[0], res[1], res[2], res[3]);
  }
}

__global__ __launch_bounds__(256) void iter_kernel(
    const float* __restrict__ Wf, const float* __restrict__ rin,
    float* __restrict__ rout, const float* __restrict__ meanv,
    const float* __restrict__ qn, const float* __restrict__ qw,
    unsigned* __restrict__ convslot)
{
  const int row  = blockIdx.x;
  const int tid  = threadIdx.x;
  const int lane = tid & 63;
  const int wvid = tid >> 6;
  __shared__ float smu[4], svar[4];
  float mu = 0.0f, var = 0.0f;
  const float* wrow = Wf + (size_t)row * NN;
  float4 w[6], r4[6]; bool have[6];
#pragma unroll
  for (int k = 0; k < 6; ++k) {
    const int j = (tid << 2) + (k << 10);
    have[k] = (j < NN);
    if (have[k]) {
      w[k]  = *reinterpret_cast<const float4*>(wrow + j);
      r4[k] = *reinterpret_cast<const float4*>(rin + j);
    }
  }
#pragma unroll
  for (int k = 0; k < 6; ++k) if (have[k]) {
    mu  += w[k].x * r4[k].x + w[k].y * r4[k].y + w[k].z * r4[k].z + w[k].w * r4[k].w;
    var += w[k].x * w[k].x * r4[k].x + w[k].y * w[k].y * r4[k].y
         + w[k].z * w[k].z * r4[k].z + w[k].w * w[k].w * r4[k].w;
  }
#pragma unroll
  for (int off = 32; off > 0; off >>= 1) {
    mu  += __shfl_xor(mu, off);
    var += __shfl_xor(var, off);
  }
  if (lane == 0) { smu[wvid] = mu; svar[wvid] = var; }
  __syncthreads();
  if (tid < 64) {
    mu  = smu[0] + smu[1] + smu[2] + smu[3];
    var = svar[0] + svar[1] + svar[2] + svar[3];
    mu += meanv[row]; var += 25.0f;
    const float sig = sqrtf(var);
    const float uu = (20.0f - mu) / sig;
    const float ll = (10.0f - mu) / sig;
    const float cc = 0.5f * (uu + ll);
    const float hh = 0.5f * (uu - ll);
    const float x = cc + hh * qn[lane];
    float term    = qw[lane] * erfcx_ref(-x);
#pragma unroll
    for (int off = 32; off > 0; off >>= 1) term += __shfl_xor(term, off);
    const float integ = hh * term;
    const float phiv  = 1.0f / (1.0f + SQRT_PI_F * fmaxf(integ, 0.0f));
    const float rold = rin[row];
    const float dx   = (phiv - rold) * 0.1f;
    const float rnew = rold + dx;
    if (lane == 0) {
      rout[row] = rnew;
      const float ratio = fabsf(dx) / fmaxf(1.0f, fabsf(rnew));
      atomicMax(convslot, __float_as_uint(ratio));
    }
  }
}

__global__ __launch_bounds__(256) void final_kernel(
    const float* __restrict__ rfin, const unsigned* __restrict__ conv,
    float* __restrict__ out)
{
  int t = blockIdx.x * 256 + threadIdx.x;
  if (t < NN) out[t] = rfin[t];
  if (t == 6000) {
    float s = 0.0f;
    for (int k = NMAXI - NAVGI; k < NMAXI; ++k)
      s += (__uint_as_float(conv[k]) < 1e-5f) ? 1.0f : 0.0f;
    out[NN] = s / 30.0f;
  }
}

extern "C" void kernel_launch(void* const* d_in, const int* in_sizes, int n_in,
                              void* d_out, int out_size, void* d_ws, size_t ws_size,
                              hipStream_t stream) {
  const float* hyper    = (const float*)d_in[0];
  const float* contrast = (const float*)d_in[1];
  const float* grat     = (const float*)d_in[2];
  const float* pref     = (const float*)d_in[3];
  const float* randu    = (const float*)d_in[4];
  float* out = (float*)d_out;

  char* ws = (char*)d_ws;
  float*    g0     = (float*)(ws + 0);       // 6144 f (r buf A + pad)
  float*    g1     = (float*)(ws + 24576);   // 6144 f (r buf B + pad)
  float*    mn     = (float*)(ws + 49152);   // 6000 f
  float*    ctab   = (float*)(ws + 73152);   // 6000 f
  float*    qn     = (float*)(ws + 97152);   // 64 f
  float*    qw     = (float*)(ws + 97408);   // 64 f
  unsigned* conv   = (unsigned*)(ws + 97664);// 80 u32 (fallback)
  unsigned* bar    = (unsigned*)(ws + 97984);// 2 u32 (barrier cnt/gen)
  float*    blkmax = (float*)(ws + 98304);   // 80*250 f
  float*    Wf     = (float*)(ws + 262144);  // fallback fp32 W

  init_kernel<<<24, 256, 0, stream>>>(contrast, grat, pref, g0, g1, mn, ctab,
                                      qn, qw, conv, bar);

  // persistent kernel (cooperative launch for co-residency guarantee)
  {
    const float* a_hyper = hyper;  const float* a_randu = randu;
    const float* a_ctab  = ctab;   const float* a_mn    = mn;
    const float* a_qn    = qn;     const float* a_qw    = qw;
    float* a_g0 = g0; float* a_g1 = g1; float* a_bm = blkmax;
    unsigned* a_bar = bar; float* a_out = out;
    void* args[11] = {&a_hyper, &a_randu, &a_ctab, &a_mn, &a_qn, &a_qw,
                      &a_g0, &a_g1, &a_bm, &a_bar, &a_out};
    hipError_t err = hipLaunchCooperativeKernel(
        (const void*)solve_kernel, dim3(NBLK), dim3(NTHR), args, 0, stream);
    if (err == hipSuccess) return;
  }

  // fallback: round-2 structure
  genw_kernel<<<NN, 256, 0, stream>>>(hyper, randu, ctab, Wf);
  float* rb[2] = {g0, g1};
  for (int t = 0; t < NMAXI; ++t) {
    const float* rin = rb[t & 1];
    float*       rou = rb[(t + 1) & 1];
    iter_kernel<<<NN, 256, 0, stream>>>(Wf, rin, rou, mn, qn, qw, conv + t);
  }
  final_kernel<<<24, 256, 0, stream>>>(rb[0], conv, out);
}